// Round 1
// baseline (147.646 us; speedup 1.0000x reference)
//
#include <hip/hip_runtime.h>
#include <math.h>

#define BB 8
#define SS 512
#define HH 768
#define NTOT (BB*SS*HH)
#define EPSBN 1e-5f

struct Params {
  const float *x, *u, *ap;
  const float *w_nor3, *g_nor3, *b_nor3;
  const float *w_nor5, *g_nor5, *b_nor5;
  const float *w_nor7, *g_nor7, *b_nor7;
  const float *wd3, *wp3, *gd3, *bd3;
  const float *wd5, *wp5, *gd5, *bd5;
  const float *wd7, *wp7, *gd7, *bd7;
  float *out;
  float *hdr;    // [0]=w_sel [1]=w_rest [2](int)=idx
  float *y;      // [B][S][H] branch pre-BN output
  float *z;      // [B][S][H] depthwise intermediate
  float *psum;   // [16][H]
  float *psq;    // [16][H]
  float *mbuf;   // [H]
  float *ibuf;   // [H] rsqrt(var+eps)
};

// ---------------- gate: Gumbel straight-through ----------------
__global__ void gate_kernel(Params p) {
  if (threadIdx.x != 0 || blockIdx.x != 0) return;
  float ap[10], lg[10], pr[10];
  float mx = -INFINITY;
  for (int i = 0; i < 10; i++) { ap[i] = p.ap[i]; mx = fmaxf(mx, ap[i]); }
  float se = 0.f;
  for (int i = 0; i < 10; i++) se += expf(ap[i] - mx);
  float lse = mx + logf(se);
  float lmax = -INFINITY;
  for (int i = 0; i < 10; i++) {
    float uc = fminf(fmaxf(p.u[i], 1e-9f), 1.f - 1e-9f);
    float gb = -logf(-logf(uc));
    lg[i] = ((ap[i] - lse) + gb) * 0.1f;   // / TEM=10
    lmax = fmaxf(lmax, lg[i]);
  }
  float ps = 0.f;
  for (int i = 0; i < 10; i++) { pr[i] = expf(lg[i] - lmax); ps += pr[i]; }
  int idx = 0; float best = -INFINITY;
  for (int i = 0; i < 10; i++) {
    pr[i] /= ps;
    if (pr[i] > best) { best = pr[i]; idx = i; }
  }
  // hardwts[j!=idx] = (0-p)+p = 0 exactly; hardwts[idx] = (1-p)+p
  float w_sel = (1.0f - pr[idx]) + pr[idx];
  p.hdr[0] = w_sel;
  p.hdr[1] = 0.0f;           // sum(w) - w_sel
  ((int*)p.hdr)[2] = idx;
}

// ---------------- idx in {0,1,2,9}: direct output ----------------
__global__ __launch_bounds__(256) void simple_kernel(Params p) {
  int idx = ((const int*)p.hdr)[2];
  if (idx >= 3 && idx <= 8) return;
  float w_sel = p.hdr[0], w_rest = p.hdr[1];
  int tid = blockIdx.x * 256 + threadIdx.x;
  if (tid >= NTOT) return;
  int bs = tid / HH;
  int s = bs % SS;
  float xv = p.x[tid];
  float sel;
  if (idx == 0) sel = 0.f;
  else if (idx == 9) sel = xv;
  else if (idx == 1) {  // avg_pool3, count_include_pad
    float xm = (s > 0) ? p.x[tid - HH] : 0.f;
    float xp = (s < SS - 1) ? p.x[tid + HH] : 0.f;
    sel = (xm + xv + xp) * (1.f / 3.f);
  } else {              // max_pool3, -inf pad
    float xm = (s > 0) ? p.x[tid - HH] : -INFINITY;
    float xp = (s < SS - 1) ? p.x[tid + HH] : -INFINITY;
    sel = fmaxf(fmaxf(xm, xv), xp);
  }
  p.out[tid] = w_sel * sel + w_rest + xv;
}

// ---------------- idx in {6,7,8}: depthwise dilated conv ----------------
__global__ __launch_bounds__(256) void dw_kernel(Params p) {
  int idx = ((const int*)p.hdr)[2];
  if (idx < 6 || idx > 8) return;
  int k = 3 + 2 * (idx - 6);
  const float* wd = (idx == 6) ? p.wd3 : (idx == 7) ? p.wd5 : p.wd7;
  int tid = blockIdx.x * 256 + threadIdx.x;
  if (tid >= NTOT) return;
  int c = tid % HH;
  int bs = tid / HH;
  int s = bs % SS;
  int b = bs / SS;
  float acc = 0.f;
  for (int dk = 0; dk < k; dk++) {
    int ss = s + 2 * dk - (k - 1);
    if (ss >= 0 && ss < SS) {
      float v = p.x[((size_t)(b * SS + ss)) * HH + c];
      acc += fmaxf(v, 0.f) * wd[c * k + dk];
    }
  }
  p.z[tid] = acc;
}

// ---------------- idx in {3..8}: GEMM producing y[b][s][o] ----------------
// nor_conv k: y[b,s,o] = sum_dk sum_i relu(x[b,s+dk-k/2,i]) * W[o,i,dk]
// dil_conv:   y[b,s,o] = sum_i z[b,s,i] * Wp[o,i]
#define TM 64
#define TN 64
#define TK 16
__global__ __launch_bounds__(256) void conv_gemm_kernel(Params p) {
  int idx = ((const int*)p.hdr)[2];
  if (idx < 3 || idx > 8) return;
  bool nor = (idx <= 5);
  int k = nor ? (3 + 2 * (idx - 3)) : (3 + 2 * (idx - 6));
  const float* W = nor ? ((idx == 3) ? p.w_nor3 : (idx == 4) ? p.w_nor5 : p.w_nor7)
                       : ((idx == 6) ? p.wp3 : (idx == 7) ? p.wp5 : p.wp7);
  const float* A = nor ? p.x : p.z;
  int taps = nor ? k : 1;
  int halo = nor ? (k >> 1) : 0;

  __shared__ float As[TK][TM + 4];
  __shared__ float Bs[TK][TN + 4];

  int bm = blockIdx.x;            // 0..63 : (b, s-tile)
  int b = bm >> 3;                // S/TM = 8 tiles
  int s0 = (bm & 7) * TM;
  int o0 = blockIdx.y * TN;

  int t = threadIdx.x;
  int lkk = t & 15;               // i within chunk
  int lr = t >> 4;                // 0..15
  int tm0 = (t & 15) * 4;
  int tn0 = (t >> 4) * 4;

  float acc[4][4];
#pragma unroll
  for (int i = 0; i < 4; i++)
#pragma unroll
    for (int j = 0; j < 4; j++) acc[i][j] = 0.f;

  for (int dk = 0; dk < taps; dk++) {
    int shift = dk - halo;
    for (int i0 = 0; i0 < HH; i0 += TK) {
      // stage A: 64 rows x 16 cols
#pragma unroll
      for (int r = 0; r < 4; r++) {
        int m = lr + 16 * r;
        int srow = s0 + m + shift;
        float v = 0.f;
        if (srow >= 0 && srow < SS) {
          float raw = A[((size_t)(b * SS + srow)) * HH + i0 + lkk];
          v = nor ? fmaxf(raw, 0.f) : raw;
        }
        As[lkk][m] = v;
      }
      // stage B: 64 outs x 16 cols
#pragma unroll
      for (int r = 0; r < 4; r++) {
        int o = o0 + lr + 16 * r;
        float wv = nor ? W[((size_t)o * HH + i0 + lkk) * k + dk]
                       : W[(size_t)o * HH + i0 + lkk];
        Bs[lkk][lr + 16 * r] = wv;
      }
      __syncthreads();
#pragma unroll
      for (int kk = 0; kk < TK; kk++) {
        float4 a = *(const float4*)&As[kk][tm0];
        float4 bv = *(const float4*)&Bs[kk][tn0];
        acc[0][0] += a.x * bv.x; acc[0][1] += a.x * bv.y; acc[0][2] += a.x * bv.z; acc[0][3] += a.x * bv.w;
        acc[1][0] += a.y * bv.x; acc[1][1] += a.y * bv.y; acc[1][2] += a.y * bv.z; acc[1][3] += a.y * bv.w;
        acc[2][0] += a.z * bv.x; acc[2][1] += a.z * bv.y; acc[2][2] += a.z * bv.z; acc[2][3] += a.z * bv.w;
        acc[3][0] += a.w * bv.x; acc[3][1] += a.w * bv.y; acc[3][2] += a.w * bv.z; acc[3][3] += a.w * bv.w;
      }
      __syncthreads();
    }
  }
#pragma unroll
  for (int mi = 0; mi < 4; mi++) {
    int m = tm0 + mi;
#pragma unroll
    for (int ni = 0; ni < 4; ni++) {
      p.y[((size_t)(b * SS + s0 + m)) * HH + o0 + tn0 + ni] = acc[mi][ni];
    }
  }
}

// ---------------- BN stats stage 1: partial sums over 256-row chunks ----------------
__global__ __launch_bounds__(256) void bn_stats1(Params p) {
  int idx = ((const int*)p.hdr)[2];
  if (idx < 3 || idx > 8) return;
  int t = threadIdx.x;
  int c = blockIdx.y * 64 + (t & 63);
  int rsub = t >> 6;  // 0..3
  float s = 0.f, q = 0.f;
  int rbase = blockIdx.x * 256 + rsub;
  for (int j = 0; j < 64; j++) {
    float v = p.y[(size_t)(rbase + 4 * j) * HH + c];
    s += v; q += v * v;
  }
  __shared__ float red[2][4][64];
  red[0][rsub][t & 63] = s;
  red[1][rsub][t & 63] = q;
  __syncthreads();
  if (t < 64) {
    float ts = red[0][0][t] + red[0][1][t] + red[0][2][t] + red[0][3][t];
    float tq = red[1][0][t] + red[1][1][t] + red[1][2][t] + red[1][3][t];
    p.psum[blockIdx.x * HH + blockIdx.y * 64 + t] = ts;
    p.psq[blockIdx.x * HH + blockIdx.y * 64 + t] = tq;
  }
}

// ---------------- BN stats stage 2: finalize mean / rsqrt(var+eps) ----------------
__global__ __launch_bounds__(256) void bn_stats2(Params p) {
  int idx = ((const int*)p.hdr)[2];
  if (idx < 3 || idx > 8) return;
  int c = blockIdx.x * 256 + threadIdx.x;
  if (c >= HH) return;
  float s = 0.f, q = 0.f;
  for (int j = 0; j < 16; j++) { s += p.psum[j * HH + c]; q += p.psq[j * HH + c]; }
  float mean = s * (1.f / 4096.f);
  float var = q * (1.f / 4096.f) - mean * mean;
  p.mbuf[c] = mean;
  p.ibuf[c] = rsqrtf(var + EPSBN);
}

// ---------------- finalize: BN apply + gate + residual ----------------
__global__ __launch_bounds__(256) void finalize_kernel(Params p) {
  int idx = ((const int*)p.hdr)[2];
  if (idx < 3 || idx > 8) return;
  const float* g = (idx == 3) ? p.g_nor3 : (idx == 4) ? p.g_nor5 : (idx == 5) ? p.g_nor7
                 : (idx == 6) ? p.gd3 : (idx == 7) ? p.gd5 : p.gd7;
  const float* be = (idx == 3) ? p.b_nor3 : (idx == 4) ? p.b_nor5 : (idx == 5) ? p.b_nor7
                  : (idx == 6) ? p.bd3 : (idx == 7) ? p.bd5 : p.bd7;
  float w_sel = p.hdr[0], w_rest = p.hdr[1];
  int tid = blockIdx.x * 256 + threadIdx.x;
  if (tid >= NTOT) return;
  int h = tid % HH;
  float yv = p.y[tid];
  float nv = (yv - p.mbuf[h]) * p.ibuf[h] * g[h] + be[h];
  p.out[tid] = w_sel * nv + w_rest + p.x[tid];
}

extern "C" void kernel_launch(void* const* d_in, const int* in_sizes, int n_in,
                              void* d_out, int out_size, void* d_ws, size_t ws_size,
                              hipStream_t stream) {
  Params p;
  p.x = (const float*)d_in[0];
  p.u = (const float*)d_in[1];
  p.ap = (const float*)d_in[2];
  p.w_nor3 = (const float*)d_in[3];  p.g_nor3 = (const float*)d_in[4];  p.b_nor3 = (const float*)d_in[5];
  p.w_nor5 = (const float*)d_in[6];  p.g_nor5 = (const float*)d_in[7];  p.b_nor5 = (const float*)d_in[8];
  p.w_nor7 = (const float*)d_in[9];  p.g_nor7 = (const float*)d_in[10]; p.b_nor7 = (const float*)d_in[11];
  p.wd3 = (const float*)d_in[12]; p.wp3 = (const float*)d_in[13]; p.gd3 = (const float*)d_in[14]; p.bd3 = (const float*)d_in[15];
  p.wd5 = (const float*)d_in[16]; p.wp5 = (const float*)d_in[17]; p.gd5 = (const float*)d_in[18]; p.bd5 = (const float*)d_in[19];
  p.wd7 = (const float*)d_in[20]; p.wp7 = (const float*)d_in[21]; p.gd7 = (const float*)d_in[22]; p.bd7 = (const float*)d_in[23];
  p.out = (float*)d_out;

  char* ws = (char*)d_ws;
  size_t off = 0;
  p.hdr = (float*)(ws + off); off += 256;
  p.y   = (float*)(ws + off); off += (size_t)NTOT * 4;
  p.z   = (float*)(ws + off); off += (size_t)NTOT * 4;
  p.psum = (float*)(ws + off); off += 16 * HH * 4;
  p.psq  = (float*)(ws + off); off += 16 * HH * 4;
  p.mbuf = (float*)(ws + off); off += HH * 4;
  p.ibuf = (float*)(ws + off); off += HH * 4;

  int nblk = (NTOT + 255) / 256;

  hipLaunchKernelGGL(gate_kernel, dim3(1), dim3(64), 0, stream, p);
  hipLaunchKernelGGL(simple_kernel, dim3(nblk), dim3(256), 0, stream, p);
  hipLaunchKernelGGL(dw_kernel, dim3(nblk), dim3(256), 0, stream, p);
  hipLaunchKernelGGL(conv_gemm_kernel, dim3(BB * SS / TM, HH / TN), dim3(256), 0, stream, p);
  hipLaunchKernelGGL(bn_stats1, dim3(16, HH / 64), dim3(256), 0, stream, p);
  hipLaunchKernelGGL(bn_stats2, dim3((HH + 255) / 256), dim3(256), 0, stream, p);
  hipLaunchKernelGGL(finalize_kernel, dim3(nblk), dim3(256), 0, stream, p);
}

// Round 2
// 144.742 us; speedup vs baseline: 1.0201x; 1.0201x over previous
//
#include <hip/hip_runtime.h>
#include <math.h>

#define BB 8
#define SS 512
#define HH 768
#define NTOT (BB*SS*HH)
#define EPSBN 1e-5f

typedef __attribute__((ext_vector_type(8))) short short8v;   // 8 bf16
typedef __attribute__((ext_vector_type(4))) float float4v;

struct Params {
  const float *x, *u, *ap;
  const float *w_nor3, *g_nor3, *b_nor3;
  const float *w_nor5, *g_nor5, *b_nor5;
  const float *w_nor7, *g_nor7, *b_nor7;
  const float *wd3, *wp3, *gd3, *bd3;
  const float *wd5, *wp5, *gd5, *bd5;
  const float *wd7, *wp7, *gd7, *bd7;
  float *out;
  float *hdr;    // [0]=w_sel [1]=w_rest [2](int)=idx
  float *y;      // [B][S][H] branch pre-BN output
  float *z;      // [B][S][H] depthwise intermediate
  float *psum;   // [16][H]
  float *psq;    // [16][H]
  float *mbuf;   // [H]
  float *ibuf;   // [H] rsqrt(var+eps)
};

__device__ __forceinline__ short f2bf(float f) {
  union { float f; unsigned u; } v; v.f = f;
  unsigned r = v.u + 0x7FFF + ((v.u >> 16) & 1);   // RNE
  return (short)(r >> 16);
}

// ---------------- gate: Gumbel straight-through ----------------
__global__ void gate_kernel(Params p) {
  if (threadIdx.x != 0 || blockIdx.x != 0) return;
  float ap[10], lg[10], pr[10];
  float mx = -INFINITY;
  for (int i = 0; i < 10; i++) { ap[i] = p.ap[i]; mx = fmaxf(mx, ap[i]); }
  float se = 0.f;
  for (int i = 0; i < 10; i++) se += expf(ap[i] - mx);
  float lse = mx + logf(se);
  float lmax = -INFINITY;
  for (int i = 0; i < 10; i++) {
    float uc = fminf(fmaxf(p.u[i], 1e-9f), 1.f - 1e-9f);
    float gb = -logf(-logf(uc));
    lg[i] = ((ap[i] - lse) + gb) * 0.1f;   // / TEM=10
    lmax = fmaxf(lmax, lg[i]);
  }
  float ps = 0.f;
  for (int i = 0; i < 10; i++) { pr[i] = expf(lg[i] - lmax); ps += pr[i]; }
  int idx = 0; float best = -INFINITY;
  for (int i = 0; i < 10; i++) {
    pr[i] /= ps;
    if (pr[i] > best) { best = pr[i]; idx = i; }
  }
  float w_sel = (1.0f - pr[idx]) + pr[idx];
  p.hdr[0] = w_sel;
  p.hdr[1] = 0.0f;           // sum(w) - w_sel = 0 exactly (fp cancellation)
  ((int*)p.hdr)[2] = idx;
}

// ---------------- idx in {6,7,8}: depthwise dilated conv ----------------
__global__ __launch_bounds__(256) void dw_kernel(Params p) {
  int idx = ((const int*)p.hdr)[2];
  if (idx < 6 || idx > 8) return;
  int k = 3 + 2 * (idx - 6);
  const float* wd = (idx == 6) ? p.wd3 : (idx == 7) ? p.wd5 : p.wd7;
  int tid = blockIdx.x * 256 + threadIdx.x;
  if (tid >= NTOT) return;
  int c = tid % HH;
  int bs = tid / HH;
  int s = bs % SS;
  int b = bs / SS;
  float acc = 0.f;
  for (int dk = 0; dk < k; dk++) {
    int ss = s + 2 * dk - (k - 1);
    if (ss >= 0 && ss < SS) {
      float v = p.x[((size_t)(b * SS + ss)) * HH + c];
      acc += fmaxf(v, 0.f) * wd[c * k + dk];
    }
  }
  p.z[tid] = acc;
}

// ---------------- idx in {3..8}: bf16 MFMA GEMM producing y[b][s][o] ----------------
// nor_conv k: y[b,s,o] = sum_dk sum_i relu(x[b,s+dk-k/2,i]) * W[o,i,dk]
// dil_conv:   y[b,s,o] = sum_i z[b,s,i] * Wp[o,i]
#define BM 128
#define BN 64
#define BK 32
#define LROW 40   // shorts per LDS row (32 + 8 pad); 80 B, 16B-aligned
__global__ __launch_bounds__(256) void conv_gemm_kernel(Params p) {
  int idx = ((const int*)p.hdr)[2];
  if (idx < 3 || idx > 8) return;
  bool nor = (idx <= 5);
  int k = nor ? (3 + 2 * (idx - 3)) : (3 + 2 * (idx - 6));
  const float* W = nor ? ((idx == 3) ? p.w_nor3 : (idx == 4) ? p.w_nor5 : p.w_nor7)
                       : ((idx == 6) ? p.wp3 : (idx == 7) ? p.wp5 : p.wp7);
  const float* A = nor ? p.x : p.z;
  int taps = nor ? k : 1;
  int halo = nor ? (k >> 1) : 0;

  __shared__ __attribute__((aligned(16))) short As[BM * LROW];
  __shared__ __attribute__((aligned(16))) short Bs[BN * LROW];

  int mt = blockIdx.x;            // 0..31
  int b = mt >> 2;                // 4 s-tiles of 128 per batch
  int s0 = (mt & 3) * BM;
  int o0 = blockIdx.y * BN;       // 12 n-tiles

  int t = threadIdx.x;
  int lane = t & 63;
  int wid = t >> 6;               // 4 waves
  int wm0 = (wid >> 1) * 64;      // wave row base in tile
  int wn0 = (wid & 1) * 32;       // wave col base in tile
  int l16 = lane & 15;
  int quad = lane >> 4;

  // staging coords
  int sa_m = t >> 1;              // 0..127
  int sa_h = t & 1;               // halves of 32 floats
  int sb_n = t >> 2;              // 0..63
  int sb_seg = t & 3;             // 4 segments of 8 floats

  float4v acc[4][2];
#pragma unroll
  for (int mi = 0; mi < 4; mi++)
#pragma unroll
    for (int ni = 0; ni < 2; ni++) acc[mi][ni] = (float4v){0.f, 0.f, 0.f, 0.f};

  for (int dk = 0; dk < taps; dk++) {
    int shift = dk - halo;
    for (int k0 = 0; k0 < HH; k0 += BK) {
      // ---- stage A: BM x BK fp32 -> bf16 (relu for nor) ----
      {
        int srow = s0 + sa_m + shift;
        float4 f[4];
        if (srow >= 0 && srow < SS) {
          const float* ap = A + ((size_t)(b * SS + srow)) * HH + k0 + sa_h * 16;
#pragma unroll
          for (int j = 0; j < 4; j++) f[j] = ((const float4*)ap)[j];
        } else {
#pragma unroll
          for (int j = 0; j < 4; j++) f[j] = (float4){0.f, 0.f, 0.f, 0.f};
        }
        short h16[16];
#pragma unroll
        for (int j = 0; j < 4; j++) {
          float vx = f[j].x, vy = f[j].y, vz = f[j].z, vw = f[j].w;
          if (nor) { vx = fmaxf(vx, 0.f); vy = fmaxf(vy, 0.f); vz = fmaxf(vz, 0.f); vw = fmaxf(vw, 0.f); }
          h16[4 * j + 0] = f2bf(vx); h16[4 * j + 1] = f2bf(vy);
          h16[4 * j + 2] = f2bf(vz); h16[4 * j + 3] = f2bf(vw);
        }
        short* dst = &As[sa_m * LROW + sa_h * 16];
        *(short8v*)dst = *(short8v*)&h16[0];
        *(short8v*)(dst + 8) = *(short8v*)&h16[8];
      }
      // ---- stage B: BN x BK fp32 -> bf16 ----
      {
        short h8[8];
        int o = o0 + sb_n;
        if (!nor) {
          const float* bp = W + (size_t)o * HH + k0 + sb_seg * 8;
          float4 f0 = ((const float4*)bp)[0];
          float4 f1 = ((const float4*)bp)[1];
          h8[0] = f2bf(f0.x); h8[1] = f2bf(f0.y); h8[2] = f2bf(f0.z); h8[3] = f2bf(f0.w);
          h8[4] = f2bf(f1.x); h8[5] = f2bf(f1.y); h8[6] = f2bf(f1.z); h8[7] = f2bf(f1.w);
        } else {
#pragma unroll
          for (int j = 0; j < 8; j++) {
            int i = k0 + sb_seg * 8 + j;
            h8[j] = f2bf(W[((size_t)o * HH + i) * k + dk]);
          }
        }
        *(short8v*)&Bs[sb_n * LROW + sb_seg * 8] = *(short8v*)&h8[0];
      }
      __syncthreads();

      // ---- fragments + MFMA ----
      short8v af[4], bf[2];
#pragma unroll
      for (int mi = 0; mi < 4; mi++)
        af[mi] = *(const short8v*)&As[(wm0 + mi * 16 + l16) * LROW + quad * 8];
#pragma unroll
      for (int ni = 0; ni < 2; ni++)
        bf[ni] = *(const short8v*)&Bs[(wn0 + ni * 16 + l16) * LROW + quad * 8];
#pragma unroll
      for (int mi = 0; mi < 4; mi++)
#pragma unroll
        for (int ni = 0; ni < 2; ni++)
          acc[mi][ni] = __builtin_amdgcn_mfma_f32_16x16x32_bf16(af[mi], bf[ni], acc[mi][ni], 0, 0, 0);
      __syncthreads();
    }
  }

  // ---- epilogue: C/D layout col=lane&15, row=quad*4+reg ----
#pragma unroll
  for (int mi = 0; mi < 4; mi++) {
#pragma unroll
    for (int ni = 0; ni < 2; ni++) {
      int col = o0 + wn0 + ni * 16 + l16;
#pragma unroll
      for (int r = 0; r < 4; r++) {
        int row = s0 + wm0 + mi * 16 + quad * 4 + r;
        p.y[((size_t)(b * SS + row)) * HH + col] = acc[mi][ni][r];
      }
    }
  }
}

// ---------------- BN stats stage 1 ----------------
__global__ __launch_bounds__(256) void bn_stats1(Params p) {
  int idx = ((const int*)p.hdr)[2];
  if (idx < 3 || idx > 8) return;
  int t = threadIdx.x;
  int c = blockIdx.y * 64 + (t & 63);
  int rsub = t >> 6;
  float s = 0.f, q = 0.f;
  int rbase = blockIdx.x * 256 + rsub;
  for (int j = 0; j < 64; j++) {
    float v = p.y[(size_t)(rbase + 4 * j) * HH + c];
    s += v; q += v * v;
  }
  __shared__ float red[2][4][64];
  red[0][rsub][t & 63] = s;
  red[1][rsub][t & 63] = q;
  __syncthreads();
  if (t < 64) {
    float ts = red[0][0][t] + red[0][1][t] + red[0][2][t] + red[0][3][t];
    float tq = red[1][0][t] + red[1][1][t] + red[1][2][t] + red[1][3][t];
    p.psum[blockIdx.x * HH + blockIdx.y * 64 + t] = ts;
    p.psq[blockIdx.x * HH + blockIdx.y * 64 + t] = tq;
  }
}

// ---------------- BN stats stage 2 ----------------
__global__ __launch_bounds__(256) void bn_stats2(Params p) {
  int idx = ((const int*)p.hdr)[2];
  if (idx < 3 || idx > 8) return;
  int c = blockIdx.x * 256 + threadIdx.x;
  if (c >= HH) return;
  float s = 0.f, q = 0.f;
  for (int j = 0; j < 16; j++) { s += p.psum[j * HH + c]; q += p.psq[j * HH + c]; }
  float mean = s * (1.f / 4096.f);
  float var = q * (1.f / 4096.f) - mean * mean;
  p.mbuf[c] = mean;
  p.ibuf[c] = rsqrtf(var + EPSBN);
}

// ---------------- epilogue: handles ALL idx ----------------
__global__ __launch_bounds__(256) void epilogue_kernel(Params p) {
  int idx = ((const int*)p.hdr)[2];
  float w_sel = p.hdr[0], w_rest = p.hdr[1];
  int tid = blockIdx.x * 256 + threadIdx.x;
  if (tid >= NTOT) return;
  float xv = p.x[tid];
  float sel;
  if (idx >= 3 && idx <= 8) {
    const float* g = (idx == 3) ? p.g_nor3 : (idx == 4) ? p.g_nor5 : (idx == 5) ? p.g_nor7
                   : (idx == 6) ? p.gd3 : (idx == 7) ? p.gd5 : p.gd7;
    const float* be = (idx == 3) ? p.b_nor3 : (idx == 4) ? p.b_nor5 : (idx == 5) ? p.b_nor7
                    : (idx == 6) ? p.bd3 : (idx == 7) ? p.bd5 : p.bd7;
    int h = tid % HH;
    float yv = p.y[tid];
    sel = (yv - p.mbuf[h]) * p.ibuf[h] * g[h] + be[h];
  } else if (idx == 0) {
    sel = 0.f;
  } else if (idx == 9) {
    sel = xv;
  } else {
    int bs = tid / HH;
    int s = bs % SS;
    if (idx == 1) {
      float xm = (s > 0) ? p.x[tid - HH] : 0.f;
      float xp = (s < SS - 1) ? p.x[tid + HH] : 0.f;
      sel = (xm + xv + xp) * (1.f / 3.f);
    } else {
      float xm = (s > 0) ? p.x[tid - HH] : -INFINITY;
      float xp = (s < SS - 1) ? p.x[tid + HH] : -INFINITY;
      sel = fmaxf(fmaxf(xm, xv), xp);
    }
  }
  p.out[tid] = w_sel * sel + w_rest + xv;
}

extern "C" void kernel_launch(void* const* d_in, const int* in_sizes, int n_in,
                              void* d_out, int out_size, void* d_ws, size_t ws_size,
                              hipStream_t stream) {
  Params p;
  p.x = (const float*)d_in[0];
  p.u = (const float*)d_in[1];
  p.ap = (const float*)d_in[2];
  p.w_nor3 = (const float*)d_in[3];  p.g_nor3 = (const float*)d_in[4];  p.b_nor3 = (const float*)d_in[5];
  p.w_nor5 = (const float*)d_in[6];  p.g_nor5 = (const float*)d_in[7];  p.b_nor5 = (const float*)d_in[8];
  p.w_nor7 = (const float*)d_in[9];  p.g_nor7 = (const float*)d_in[10]; p.b_nor7 = (const float*)d_in[11];
  p.wd3 = (const float*)d_in[12]; p.wp3 = (const float*)d_in[13]; p.gd3 = (const float*)d_in[14]; p.bd3 = (const float*)d_in[15];
  p.wd5 = (const float*)d_in[16]; p.wp5 = (const float*)d_in[17]; p.gd5 = (const float*)d_in[18]; p.bd5 = (const float*)d_in[19];
  p.wd7 = (const float*)d_in[20]; p.wp7 = (const float*)d_in[21]; p.gd7 = (const float*)d_in[22]; p.bd7 = (const float*)d_in[23];
  p.out = (float*)d_out;

  char* ws = (char*)d_ws;
  size_t off = 0;
  p.hdr = (float*)(ws + off); off += 256;
  p.y   = (float*)(ws + off); off += (size_t)NTOT * 4;
  p.z   = (float*)(ws + off); off += (size_t)NTOT * 4;
  p.psum = (float*)(ws + off); off += 16 * HH * 4;
  p.psq  = (float*)(ws + off); off += 16 * HH * 4;
  p.mbuf = (float*)(ws + off); off += HH * 4;
  p.ibuf = (float*)(ws + off); off += HH * 4;

  int nblk = (NTOT + 255) / 256;

  hipLaunchKernelGGL(gate_kernel, dim3(1), dim3(64), 0, stream, p);
  hipLaunchKernelGGL(dw_kernel, dim3(nblk), dim3(256), 0, stream, p);
  hipLaunchKernelGGL(conv_gemm_kernel, dim3(32, HH / BN), dim3(256), 0, stream, p);
  hipLaunchKernelGGL(bn_stats1, dim3(16, HH / 64), dim3(256), 0, stream, p);
  hipLaunchKernelGGL(bn_stats2, dim3((HH + 255) / 256), dim3(256), 0, stream, p);
  hipLaunchKernelGGL(epilogue_kernel, dim3(nblk), dim3(256), 0, stream, p);
}